// Round 7
// baseline (158.921 us; speedup 1.0000x reference)
//
#include <hip/hip_runtime.h>
#include <hip/hip_bf16.h>
#include <cstdint>

typedef unsigned short u16;
typedef __attribute__((ext_vector_type(8))) short bf16x8;
typedef __attribute__((ext_vector_type(4))) float f32x4;

#define S_LEN 1024
#define BATCH 8
#define DMODEL 256
#define NHEAD 8
#define HDIM 32
#define DFF 1024
#define NROWS (S_LEN * BATCH)   // 8192

static __device__ __forceinline__ u16 f2b(float f) {
    union { float f; unsigned u; } x{f};
    unsigned r = (x.u + 0x7fffu + ((x.u >> 16) & 1u)) >> 16;
    return (u16)r;
}

// ---------------------------------------------------------------------------
// Fused prep: blocks [0,2048) = LayerNorm1 (4 rows/block);
//             blocks [2048,2816) = weight f32->bf16 convert (q-scale folded).
// ---------------------------------------------------------------------------
__global__ __launch_bounds__(256) void prep_kernel(
    const float* __restrict__ in, const float* __restrict__ g1,
    const float* __restrict__ be1, float* __restrict__ of, u16* __restrict__ ob,
    const float* __restrict__ ipw, const float* __restrict__ outw,
    const float* __restrict__ w1, const float* __restrict__ w2,
    const float* __restrict__ ipb,
    u16* __restrict__ wqkv, u16* __restrict__ wout,
    u16* __restrict__ w1b, u16* __restrict__ w2b, float* __restrict__ bq)
{
    const float s = 0.17677669529663689f; // 1/sqrt(32)
    if (blockIdx.x >= 2048) {
        const int i4 = ((int)blockIdx.x - 2048) * 1024 + threadIdx.x * 4;
        const float* src; u16* dst; int off; float sc = 1.0f;
        if (i4 < 196608)      { src = ipw;  dst = wqkv; off = 0;      if (i4 < 65536) sc = s; }
        else if (i4 < 262144) { src = outw; dst = wout; off = 196608; }
        else if (i4 < 524288) { src = w1;   dst = w1b;  off = 262144; }
        else                  { src = w2;   dst = w2b;  off = 524288; }
        const float4 v = *(const float4*)(src + i4 - off);
        uint2 pk;
        pk.x = (unsigned)f2b(v.x * sc) | ((unsigned)f2b(v.y * sc) << 16);
        pk.y = (unsigned)f2b(v.z * sc) | ((unsigned)f2b(v.w * sc) << 16);
        *(uint2*)(dst + i4 - off) = pk;
        if (i4 < 768) {
            const float4 b = *(const float4*)(ipb + i4);
            const float bs = (i4 < 256) ? s : 1.0f;
            *(float4*)(bq + i4) = make_float4(b.x * bs, b.y * bs, b.z * bs, b.w * bs);
        }
        return;
    }
    const int w = threadIdx.x >> 6, l = threadIdx.x & 63;
    const int row = blockIdx.x * 4 + w;
    const float4 v = *(const float4*)(in + (size_t)row * DMODEL + l * 4);
    float s0 = v.x + v.y + v.z + v.w;
    #pragma unroll
    for (int o = 32; o; o >>= 1) s0 += __shfl_xor(s0, o);
    const float mu = s0 * (1.0f / DMODEL);
    const float dx = v.x - mu, dy = v.y - mu, dz = v.z - mu, dw = v.w - mu;
    float sq = dx * dx + dy * dy + dz * dz + dw * dw;
    #pragma unroll
    for (int o = 32; o; o >>= 1) sq += __shfl_xor(sq, o);
    const float rs = rsqrtf(sq * (1.0f / DMODEL) + 1e-5f);
    const float4 gv = *(const float4*)(g1 + l * 4);
    const float4 bv = *(const float4*)(be1 + l * 4);
    const float r0 = dx * rs * gv.x + bv.x;
    const float r1 = dy * rs * gv.y + bv.y;
    const float r2 = dz * rs * gv.z + bv.z;
    const float r3 = dw * rs * gv.w + bv.w;
    *(float4*)(of + (size_t)row * DMODEL + l * 4) = make_float4(r0, r1, r2, r3);
    uint2 pk;
    pk.x = (unsigned)f2b(r0) | ((unsigned)f2b(r1) << 16);
    pk.y = (unsigned)f2b(r2) | ((unsigned)f2b(r3) << 16);
    *(uint2*)(ob + (size_t)row * DMODEL + l * 4) = pk;
}

// ---------------------------------------------------------------------------
// Shared GEMM core: tile MF*64 (M) x 64 (N), BK=64 chunks, double-buffered
// LDS B with register prefetch (1 barrier per chunk). mfma(B,A) transposed
// accumulator: lane q = output row, g*4+r = output col within n-fragment.
// ---------------------------------------------------------------------------
template <int MF>
__device__ __forceinline__ void gemm_core(
    const u16* __restrict__ A, const u16* __restrict__ Bw,
    int N, int K, int nbase, int rowbase, u16* sB, f32x4 acc[MF][4])
{
    const int tid = threadIdx.x, w = tid >> 6, l = tid & 63;
    const int g = l >> 4, q = l & 15;
    const u16* Arow = A + (size_t)(rowbase + w * (MF * 16) + q) * K + g * 8;

    const int sbr = tid >> 3, sseg = tid & 7;
    const size_t bsrc0 = (size_t)(nbase + sbr) * K + sseg * 8;
    const size_t bsrc1 = (size_t)(nbase + sbr + 32) * K + sseg * 8;
    const int d0 = sbr * 128 + ((sseg * 16) ^ ((sbr & 7) << 4));
    const int d1 = d0 + 32 * 128;

    {
        const uint4 r0 = *(const uint4*)(Bw + bsrc0);
        const uint4 r1 = *(const uint4*)(Bw + bsrc1);
        *(uint4*)((char*)sB + d0) = r0;
        *(uint4*)((char*)sB + d1) = r1;
    }
    const int NC = K >> 6;
    for (int c = 0; c < NC; ++c) {
        __syncthreads();
        char* sBc = (char*)sB + (c & 1) * 8192;
        char* sBn = (char*)sB + ((c + 1) & 1) * 8192;
        uint4 p0, p1;
        if (c + 1 < NC) {
            p0 = *(const uint4*)(Bw + bsrc0 + (c + 1) * 64);
            p1 = *(const uint4*)(Bw + bsrc1 + (c + 1) * 64);
        }
        const int kk = c * 64;
        #pragma unroll
        for (int ks = 0; ks < 2; ++ks) {
            bf16x8 af[MF];
            #pragma unroll
            for (int m = 0; m < MF; ++m)
                af[m] = *(const bf16x8*)(Arow + (size_t)m * 16 * K + kk + ks * 32);
            #pragma unroll
            for (int n = 0; n < 4; ++n) {
                const int rr = n * 16 + q;
                const bf16x8 bf = *(const bf16x8*)(
                    sBc + rr * 128 + ((ks * 64 + g * 16) ^ ((rr & 7) << 4)));
                #pragma unroll
                for (int m = 0; m < MF; ++m)
                    acc[m][n] = __builtin_amdgcn_mfma_f32_16x16x32_bf16(bf, af[m], acc[m][n], 0, 0, 0);
            }
        }
        if (c + 1 < NC) {
            *(uint4*)(sBn + d0) = p0;
            *(uint4*)(sBn + d1) = p1;
        }
    }
}

// ---------------------------------------------------------------------------
// QKV GEMM (tile 128x64): head-contiguous epilogue -> Qh/Kh [BH,S,32], Vt [BH,32,S].
// grid (64, 12).
// ---------------------------------------------------------------------------
__global__ __launch_bounds__(256) void gemm_qkv(
    const u16* __restrict__ A, const u16* __restrict__ Bw,
    const float* __restrict__ bias,
    u16* __restrict__ Qh, u16* __restrict__ Kh, u16* __restrict__ Vt)
{
    __shared__ u16 sB[2][64 * 64];
    const int tid = threadIdx.x, w = tid >> 6, l = tid & 63;
    const int g = l >> 4, q = l & 15;
    const int rowbase = blockIdx.x * 128, nbase = blockIdx.y * 64;
    f32x4 acc[2][4] = {};
    gemm_core<2>(A, Bw, 768, 256, nbase, rowbase, &sB[0][0], acc);

    #pragma unroll
    for (int m = 0; m < 2; ++m) {
        const int row = rowbase + w * 32 + m * 16 + q;
        const int s = row >> 3, b = row & 7;
        if (nbase < 512) {
            u16* dst = (nbase >= 256) ? Kh : Qh;
            #pragma unroll
            for (int n = 0; n < 4; ++n) {
                const int col = nbase + n * 16 + g * 4;
                const float4 bv = *(const float4*)(bias + col);
                const int cc = col & 255, h = cc >> 5, hd = cc & 31;
                const int bh = b * 8 + h;
                uint2 pk;
                pk.x = (unsigned)f2b(acc[m][n][0] + bv.x) | ((unsigned)f2b(acc[m][n][1] + bv.y) << 16);
                pk.y = (unsigned)f2b(acc[m][n][2] + bv.z) | ((unsigned)f2b(acc[m][n][3] + bv.w) << 16);
                *(uint2*)(dst + ((size_t)bh * S_LEN + s) * HDIM + hd) = pk;
            }
        } else {
            #pragma unroll
            for (int n = 0; n < 4; ++n) {
                const int col = nbase + n * 16 + g * 4;
                const float4 bv = *(const float4*)(bias + col);
                const int cc = col - 512, h = cc >> 5, hd = cc & 31;
                const int bh = b * 8 + h;
                Vt[((size_t)bh * HDIM + hd + 0) * S_LEN + s] = f2b(acc[m][n][0] + bv.x);
                Vt[((size_t)bh * HDIM + hd + 1) * S_LEN + s] = f2b(acc[m][n][1] + bv.y);
                Vt[((size_t)bh * HDIM + hd + 2) * S_LEN + s] = f2b(acc[m][n][2] + bv.z);
                Vt[((size_t)bh * HDIM + hd + 3) * S_LEN + s] = f2b(acc[m][n][3] + bv.w);
            }
        }
    }
}

// ---------------------------------------------------------------------------
// Flash attention: LDS-staged K/V in MFMA-fragment order (conflict-free b128,
// double-buffered, async-split), lane-local softmax, pipelined nontemporal
// bias stream. grid (S/64, B*H), 256 thr (4 waves x 16 q-rows).
// ---------------------------------------------------------------------------
__global__ __launch_bounds__(256) void attn_kernel(
    const u16* __restrict__ Qh, const u16* __restrict__ Kh,
    const u16* __restrict__ Vt, const float* __restrict__ bias,
    u16* __restrict__ ctx)
{
    __shared__ u16 sK[2][64 * 32];
    __shared__ u16 sV[2][32 * 64];
    __shared__ u16 sP[4][16 * 64];
    const int tid = threadIdx.x, w = tid >> 6, l = tid & 63;
    const int g = l >> 4, q = l & 15;
    const int bh = blockIdx.y, b = bh >> 3, h = bh & 7;
    const int qbase = blockIdx.x * 64 + w * 16;
    const int qrow = qbase + q;

    const bf16x8 qf = *(const bf16x8*)(Qh + ((size_t)bh * S_LEN + qrow) * HDIM + g * 8);
    const float* brow = bias + ((size_t)bh * S_LEN + qrow) * S_LEN;
    u16* Pw = sP[w];
    const int swz = (q & 7) << 4;

    const u16* KsrcBase = Kh + ((size_t)bh * S_LEN + w * 16 + q) * HDIM + g * 8;
    const u16* VsrcBase = Vt + ((size_t)bh * HDIM + (w & 1) * 16 + q) * S_LEN
                             + (w >> 1) * 32 + g * 8;
    u16* KdstA = &sK[0][tid * 8]; u16* KdstB = &sK[1][tid * 8];
    u16* VdstA = &sV[0][tid * 8]; u16* VdstB = &sV[1][tid * 8];

    f32x4 ctxa[2] = {{0,0,0,0},{0,0,0,0}};
    float m = -1e30f, lsum = 0.f;

    auto loadB = [&](int kt, f32x4* bv) {
        #pragma unroll
        for (int n = 0; n < 4; ++n)
            bv[n] = __builtin_nontemporal_load(
                (const f32x4*)(brow + kt * 64 + n * 16 + g * 4));
    };

    auto proc = [&](int buf, const f32x4* bv) {
        f32x4 sc[4];
        #pragma unroll
        for (int n = 0; n < 4; ++n) {
            const bf16x8 kf = *(const bf16x8*)(&sK[buf][(n * 64 + l) * 8]);
            f32x4 z = {0, 0, 0, 0};
            sc[n] = __builtin_amdgcn_mfma_f32_16x16x32_bf16(kf, qf, z, 0, 0, 0);
        }
        #pragma unroll
        for (int n = 0; n < 4; ++n)
            #pragma unroll
            for (int r = 0; r < 4; ++r) sc[n][r] += bv[n][r];

        float mx = sc[0][0];
        #pragma unroll
        for (int n = 0; n < 4; ++n)
            #pragma unroll
            for (int r = 0; r < 4; ++r) mx = fmaxf(mx, sc[n][r]);
        mx = fmaxf(mx, __shfl_xor(mx, 16));
        mx = fmaxf(mx, __shfl_xor(mx, 32));
        const float mn = fmaxf(m, mx);
        const float corr = __expf(m - mn);
        float su = 0.f;
        u16 pb[16];
        #pragma unroll
        for (int n = 0; n < 4; ++n)
            #pragma unroll
            for (int r = 0; r < 4; ++r) {
                const float pv = __expf(sc[n][r] - mn);
                su += pv;
                pb[n * 4 + r] = f2b(pv);
            }
        su += __shfl_xor(su, 16);
        su += __shfl_xor(su, 32);
        lsum = lsum * corr + su;
        m = mn;
        #pragma unroll
        for (int jg = 0; jg < 2; ++jg)
            #pragma unroll
            for (int r = 0; r < 4; ++r) ctxa[jg][r] *= corr;

        #pragma unroll
        for (int n = 0; n < 4; ++n) {
            uint2 pk;
            pk.x = (unsigned)pb[n * 4] | ((unsigned)pb[n * 4 + 1] << 16);
            pk.y = (unsigned)pb[n * 4 + 2] | ((unsigned)pb[n * 4 + 3] << 16);
            *(uint2*)((char*)Pw + q * 128 + ((n * 32 + g * 8) ^ swz)) = pk;
        }

        #pragma unroll
        for (int ks = 0; ks < 2; ++ks) {
            const bf16x8 pf = *(const bf16x8*)((char*)Pw + q * 128 + ((ks * 64 + g * 16) ^ swz));
            #pragma unroll
            for (int jg = 0; jg < 2; ++jg) {
                const bf16x8 vf = *(const bf16x8*)(&sV[buf][((ks * 2 + jg) * 64 + l) * 8]);
                ctxa[jg] = __builtin_amdgcn_mfma_f32_16x16x32_bf16(vf, pf, ctxa[jg], 0, 0, 0);
            }
        }
    };

    f32x4 bv0[4], bv1[4];
    {
        const uint4 kr = *(const uint4*)(KsrcBase);
        const uint4 vr = *(const uint4*)(VsrcBase);
        *(uint4*)KdstA = kr;
        *(uint4*)VdstA = vr;
        loadB(0, bv0);
    }
    __syncthreads();

    for (int kt = 0; kt < 16; kt += 2) {
        {
            uint4 kr, vr;
            kr = *(const uint4*)(KsrcBase + (size_t)(kt + 1) * 64 * HDIM);
            vr = *(const uint4*)(VsrcBase + (size_t)(kt + 1) * 64);
            loadB(kt + 1, bv1);
            proc(0, bv0);
            *(uint4*)KdstB = kr;
            *(uint4*)VdstB = vr;
        }
        __syncthreads();
        {
            uint4 kr, vr;
            if (kt + 2 < 16) {
                kr = *(const uint4*)(KsrcBase + (size_t)(kt + 2) * 64 * HDIM);
                vr = *(const uint4*)(VsrcBase + (size_t)(kt + 2) * 64);
                loadB(kt + 2, bv0);
            }
            proc(1, bv1);
            if (kt + 2 < 16) {
                *(uint4*)KdstA = kr;
                *(uint4*)VdstA = vr;
            }
        }
        __syncthreads();
    }

    const float inv = 1.0f / lsum;
    #pragma unroll
    for (int jg = 0; jg < 2; ++jg) {
        uint2 pk;
        pk.x = (unsigned)f2b(ctxa[jg][0] * inv) | ((unsigned)f2b(ctxa[jg][1] * inv) << 16);
        pk.y = (unsigned)f2b(ctxa[jg][2] * inv) | ((unsigned)f2b(ctxa[jg][3] * inv) << 16);
        *(uint2*)(ctx + ((size_t)qrow * 8 + b) * DMODEL + h * 32 + jg * 16 + g * 4) = pk;
    }
}

// ---------------------------------------------------------------------------
// Fused out-proj + residual(xf) + LayerNorm2 -> yf (f32), yb (bf16).
// 32 rows/block (2 row-frags/wave), grid 256: halves wob re-read traffic.
// ---------------------------------------------------------------------------
__global__ __launch_bounds__(256) void oproj_ln(
    const u16* __restrict__ ctx, const u16* __restrict__ wob,
    const float* __restrict__ ob, const float* __restrict__ xf,
    const float* __restrict__ g2, const float* __restrict__ be2,
    float* __restrict__ yf, u16* __restrict__ yb)
{
    __shared__ float s1[4][32], s2[4][32];
    const int tid = threadIdx.x, wv = tid >> 6, l = tid & 63;
    const int g = l >> 4, q = l & 15;
    const int rowbase = blockIdx.x * 32;
    f32x4 acc[2][4] = {};
    const u16* Arow = ctx + (size_t)(rowbase + q) * 256 + g * 8;
    const u16* Brow = wob + (size_t)(wv * 64 + q) * 256 + g * 8;

    #pragma unroll 2
    for (int kk = 0; kk < 256; kk += 32) {
        bf16x8 af[2];
        #pragma unroll
        for (int m = 0; m < 2; ++m)
            af[m] = *(const bf16x8*)(Arow + (size_t)m * 16 * 256 + kk);
        #pragma unroll
        for (int n = 0; n < 4; ++n) {
            const bf16x8 bf = *(const bf16x8*)(Brow + (size_t)n * 16 * 256 + kk);
            #pragma unroll
            for (int m = 0; m < 2; ++m)
                acc[m][n] = __builtin_amdgcn_mfma_f32_16x16x32_bf16(bf, af[m], acc[m][n], 0, 0, 0);
        }
    }

    float sum[2] = {0.f, 0.f};
    #pragma unroll
    for (int m = 0; m < 2; ++m) {
        const int row = rowbase + m * 16 + q;
        #pragma unroll
        for (int n = 0; n < 4; ++n) {
            const int col = wv * 64 + n * 16 + g * 4;
            const float4 bv = *(const float4*)(ob + col);
            const float4 rv = *(const float4*)(xf + (size_t)row * 256 + col);
            acc[m][n][0] += bv.x + rv.x; acc[m][n][1] += bv.y + rv.y;
            acc[m][n][2] += bv.z + rv.z; acc[m][n][3] += bv.w + rv.w;
            sum[m] += acc[m][n][0] + acc[m][n][1] + acc[m][n][2] + acc[m][n][3];
        }
        sum[m] += __shfl_xor(sum[m], 16);
        sum[m] += __shfl_xor(sum[m], 32);
    }
    if (l < 16) { s1[wv][q] = sum[0]; s1[wv][16 + q] = sum[1]; }
    __syncthreads();
    float mu[2], rs[2];
    #pragma unroll
    for (int m = 0; m < 2; ++m) {
        const int lr = m * 16 + q;
        mu[m] = (s1[0][lr] + s1[1][lr] + s1[2][lr] + s1[3][lr]) * (1.0f / 256);
    }
    float sq[2] = {0.f, 0.f};
    #pragma unroll
    for (int m = 0; m < 2; ++m) {
        #pragma unroll
        for (int n = 0; n < 4; ++n)
            #pragma unroll
            for (int r = 0; r < 4; ++r) {
                const float d = acc[m][n][r] - mu[m];
                sq[m] += d * d;
            }
        sq[m] += __shfl_xor(sq[m], 16);
        sq[m] += __shfl_xor(sq[m], 32);
    }
    if (l < 16) { s2[wv][q] = sq[0]; s2[wv][16 + q] = sq[1]; }
    __syncthreads();
    #pragma unroll
    for (int m = 0; m < 2; ++m) {
        const int lr = m * 16 + q;
        rs[m] = rsqrtf((s2[0][lr] + s2[1][lr] + s2[2][lr] + s2[3][lr]) * (1.0f / 256) + 1e-5f);
    }

    #pragma unroll
    for (int m = 0; m < 2; ++m) {
        const int row = rowbase + m * 16 + q;
        #pragma unroll
        for (int n = 0; n < 4; ++n) {
            const int col = wv * 64 + n * 16 + g * 4;
            const float4 gv = *(const float4*)(g2 + col);
            const float4 b2 = *(const float4*)(be2 + col);
            const float y0 = (acc[m][n][0] - mu[m]) * rs[m] * gv.x + b2.x;
            const float y1 = (acc[m][n][1] - mu[m]) * rs[m] * gv.y + b2.y;
            const float y2 = (acc[m][n][2] - mu[m]) * rs[m] * gv.z + b2.z;
            const float y3 = (acc[m][n][3] - mu[m]) * rs[m] * gv.w + b2.w;
            *(float4*)(yf + (size_t)row * 256 + col) = make_float4(y0, y1, y2, y3);
            uint2 pk;
            pk.x = (unsigned)f2b(y0) | ((unsigned)f2b(y1) << 16);
            pk.y = (unsigned)f2b(y2) | ((unsigned)f2b(y3) << 16);
            *(uint2*)(yb + (size_t)row * 256 + col) = pk;
        }
    }
}

// ---------------------------------------------------------------------------
// Fused FFN: out = relu(yb@W1^T+b1)@W2^T + b2 + yf.  32 rows/block, grid 256,
// 512 thr (8 waves). h [32][1024] bf16 lives in LDS (64 KB, XOR-swizzled);
// W1/W2 (512 KB each) stream from per-XCD L2. Saves hb HBM round-trip.
// ---------------------------------------------------------------------------
__global__ __launch_bounds__(512) void ffn_fused(
    const u16* __restrict__ yb, const u16* __restrict__ w1b,
    const float* __restrict__ b1, const u16* __restrict__ w2b,
    const float* __restrict__ b2, const float* __restrict__ yf,
    float* __restrict__ out)
{
    __shared__ u16 sH[32 * 1024];   // row stride 2048 B, XOR-swizzled per 128B
    const int tid = threadIdx.x, w = tid >> 6, l = tid & 63;
    const int g = l >> 4, q = l & 15;
    const int rowbase = blockIdx.x * 32;

    // ---- FFN1: h[32][1024], wave w computes cols w*128 .. w*128+127
    {
        const int cbase = w * 128;
        f32x4 acc[2][8] = {};
        const u16* Arow = yb + (size_t)(rowbase + q) * 256 + g * 8;
        const u16* Brow = w1b + (size_t)(cbase + q) * 256 + g * 8;
        #pragma unroll 2
        for (int kk = 0; kk < 256; kk += 32) {
            bf16x8 af[2];
            #pragma unroll
            for (int m = 0; m < 2; ++m)
                af[m] = *(const bf16x8*)(Arow + (size_t)m * 16 * 256 + kk);
            #pragma unroll
            for (int n = 0; n < 8; ++n) {
                const bf16x8 bf = *(const bf16x8*)(Brow + (size_t)n * 16 * 256 + kk);
                #pragma unroll
                for (int m = 0; m < 2; ++m)
                    acc[m][n] = __builtin_amdgcn_mfma_f32_16x16x32_bf16(bf, af[m], acc[m][n], 0, 0, 0);
            }
        }
        // epilogue: +b1, relu, pack -> swizzled LDS
        #pragma unroll
        for (int m = 0; m < 2; ++m) {
            const int lr = m * 16 + q;
            #pragma unroll
            for (int n = 0; n < 8; ++n) {
                const int col = cbase + n * 16 + g * 4;
                const float4 bv = *(const float4*)(b1 + col);
                const float v0 = fmaxf(acc[m][n][0] + bv.x, 0.f);
                const float v1 = fmaxf(acc[m][n][1] + bv.y, 0.f);
                const float v2 = fmaxf(acc[m][n][2] + bv.z, 0.f);
                const float v3 = fmaxf(acc[m][n][3] + bv.w, 0.f);
                uint2 pk;
                pk.x = (unsigned)f2b(v0) | ((unsigned)f2b(v1) << 16);
                pk.y = (unsigned)f2b(v2) | ((unsigned)f2b(v3) << 16);
                const int x = col * 2;   // byte offset within row
                const int sx = (x & ~127) | ((x & 127) ^ ((lr & 7) << 4));
                *(uint2*)((char*)sH + lr * 2048 + sx) = pk;
            }
        }
    }
    __syncthreads();

    // ---- FFN2: out[32][256], wave w computes cols w*32 .. w*32+31, K=1024
    {
        const int obase = w * 32;
        f32x4 acc[2][2] = {};
        const u16* Brow = w2b + (size_t)(obase + q) * 1024 + g * 8;
        for (int kk = 0; kk < 1024; kk += 32) {
            bf16x8 af[2];
            #pragma unroll
            for (int m = 0; m < 2; ++m) {
                const int lr = m * 16 + q;
                const int x = (kk + g * 8) * 2;
                const int sx = (x & ~127) | ((x & 127) ^ ((lr & 7) << 4));
                af[m] = *(const bf16x8*)((char*)sH + lr * 2048 + sx);
            }
            #pragma unroll
            for (int n = 0; n < 2; ++n) {
                const bf16x8 bf = *(const bf16x8*)(Brow + (size_t)n * 16 * 1024 + kk);
                #pragma unroll
                for (int m = 0; m < 2; ++m)
                    acc[m][n] = __builtin_amdgcn_mfma_f32_16x16x32_bf16(bf, af[m], acc[m][n], 0, 0, 0);
            }
        }
        #pragma unroll
        for (int m = 0; m < 2; ++m) {
            const int row = rowbase + m * 16 + q;
            #pragma unroll
            for (int n = 0; n < 2; ++n) {
                const int col = obase + n * 16 + g * 4;
                const float4 bv = *(const float4*)(b2 + col);
                const float4 rv = *(const float4*)(yf + (size_t)row * 256 + col);
                *(float4*)(out + (size_t)row * 256 + col) = make_float4(
                    acc[m][n][0] + bv.x + rv.x, acc[m][n][1] + bv.y + rv.y,
                    acc[m][n][2] + bv.z + rv.z, acc[m][n][3] + bv.w + rv.w);
            }
        }
    }
}

// ---------------------------------------------------------------------------
extern "C" void kernel_launch(void* const* d_in, const int* in_sizes, int n_in,
                              void* d_out, int out_size, void* d_ws, size_t ws_size,
                              hipStream_t stream)
{
    const float* src  = (const float*)d_in[0];
    const float* bias = (const float*)d_in[1];
    const float* ipw  = (const float*)d_in[2];
    const float* ipb  = (const float*)d_in[3];
    const float* outw = (const float*)d_in[4];
    const float* outb = (const float*)d_in[5];
    const float* w1   = (const float*)d_in[6];
    const float* b1   = (const float*)d_in[7];
    const float* w2   = (const float*)d_in[8];
    const float* b2   = (const float*)d_in[9];
    const float* g1   = (const float*)d_in[10];
    const float* be1  = (const float*)d_in[11];
    const float* g2   = (const float*)d_in[12];
    const float* be2  = (const float*)d_in[13];

    char* p = (char*)d_ws;
    auto alloc = [&](size_t bytes) -> void* {
        void* r = (void*)p;
        p += (bytes + 255) & ~(size_t)255;
        return r;
    };
    float* xf   = (float*)alloc((size_t)NROWS * DMODEL * 4);
    u16*   xb   = (u16*)  alloc((size_t)NROWS * DMODEL * 2);
    u16*   Qh   = (u16*)  alloc((size_t)64 * S_LEN * HDIM * 2);
    u16*   Kb   = (u16*)  alloc((size_t)64 * S_LEN * HDIM * 2);
    u16*   Vt   = (u16*)  alloc((size_t)64 * S_LEN * HDIM * 2);
    u16*   ctx  = (u16*)  alloc((size_t)NROWS * DMODEL * 2);
    float* yf   = (float*)alloc((size_t)NROWS * DMODEL * 4);
    u16*   yb   = (u16*)  alloc((size_t)NROWS * DMODEL * 2);
    u16*   wqkv = (u16*)  alloc((size_t)768 * 256 * 2);
    u16*   wob  = (u16*)  alloc((size_t)256 * 256 * 2);
    u16*   w1b  = (u16*)  alloc((size_t)1024 * 256 * 2);
    u16*   w2b  = (u16*)  alloc((size_t)256 * 1024 * 2);
    float* bq   = (float*)alloc(768 * 4);

    prep_kernel<<<2816, 256, 0, stream>>>(src, g1, be1, xf, xb,
                                          ipw, outw, w1, w2, ipb,
                                          wqkv, wob, w1b, w2b, bq);
    gemm_qkv<<<dim3(64, 12), 256, 0, stream>>>(xb, wqkv, bq, Qh, Kb, Vt);
    attn_kernel<<<dim3(16, 64), 256, 0, stream>>>(Qh, Kb, Vt, bias, ctx);
    oproj_ln<<<256, 256, 0, stream>>>(ctx, wob, outb, xf, g2, be2, yf, yb);
    ffn_fused<<<256, 512, 0, stream>>>(yb, w1b, b1, w2b, b2, yf, (float*)d_out);
}

// Round 8
// 157.254 us; speedup vs baseline: 1.0106x; 1.0106x over previous
//
#include <hip/hip_runtime.h>
#include <hip/hip_bf16.h>
#include <cstdint>

typedef unsigned short u16;
typedef __attribute__((ext_vector_type(8))) short bf16x8;
typedef __attribute__((ext_vector_type(4))) float f32x4;

#define S_LEN 1024
#define BATCH 8
#define DMODEL 256
#define NHEAD 8
#define HDIM 32
#define DFF 1024
#define NROWS (S_LEN * BATCH)   // 8192

static __device__ __forceinline__ u16 f2b(float f) {
    union { float f; unsigned u; } x{f};
    unsigned r = (x.u + 0x7fffu + ((x.u >> 16) & 1u)) >> 16;
    return (u16)r;
}

// ---------------------------------------------------------------------------
// Fused prep: blocks [0,2048) = LayerNorm1 (4 rows/block);
//             blocks [2048,2816) = weight f32->bf16 convert (q-scale folded).
// ---------------------------------------------------------------------------
__global__ __launch_bounds__(256) void prep_kernel(
    const float* __restrict__ in, const float* __restrict__ g1,
    const float* __restrict__ be1, float* __restrict__ of, u16* __restrict__ ob,
    const float* __restrict__ ipw, const float* __restrict__ outw,
    const float* __restrict__ w1, const float* __restrict__ w2,
    const float* __restrict__ ipb,
    u16* __restrict__ wqkv, u16* __restrict__ wout,
    u16* __restrict__ w1b, u16* __restrict__ w2b, float* __restrict__ bq)
{
    const float s = 0.17677669529663689f; // 1/sqrt(32)
    if (blockIdx.x >= 2048) {
        const int i4 = ((int)blockIdx.x - 2048) * 1024 + threadIdx.x * 4;
        const float* src; u16* dst; int off; float sc = 1.0f;
        if (i4 < 196608)      { src = ipw;  dst = wqkv; off = 0;      if (i4 < 65536) sc = s; }
        else if (i4 < 262144) { src = outw; dst = wout; off = 196608; }
        else if (i4 < 524288) { src = w1;   dst = w1b;  off = 262144; }
        else                  { src = w2;   dst = w2b;  off = 524288; }
        const float4 v = *(const float4*)(src + i4 - off);
        uint2 pk;
        pk.x = (unsigned)f2b(v.x * sc) | ((unsigned)f2b(v.y * sc) << 16);
        pk.y = (unsigned)f2b(v.z * sc) | ((unsigned)f2b(v.w * sc) << 16);
        *(uint2*)(dst + i4 - off) = pk;
        if (i4 < 768) {
            const float4 b = *(const float4*)(ipb + i4);
            const float bs = (i4 < 256) ? s : 1.0f;
            *(float4*)(bq + i4) = make_float4(b.x * bs, b.y * bs, b.z * bs, b.w * bs);
        }
        return;
    }
    const int w = threadIdx.x >> 6, l = threadIdx.x & 63;
    const int row = blockIdx.x * 4 + w;
    const float4 v = *(const float4*)(in + (size_t)row * DMODEL + l * 4);
    float s0 = v.x + v.y + v.z + v.w;
    #pragma unroll
    for (int o = 32; o; o >>= 1) s0 += __shfl_xor(s0, o);
    const float mu = s0 * (1.0f / DMODEL);
    const float dx = v.x - mu, dy = v.y - mu, dz = v.z - mu, dw = v.w - mu;
    float sq = dx * dx + dy * dy + dz * dz + dw * dw;
    #pragma unroll
    for (int o = 32; o; o >>= 1) sq += __shfl_xor(sq, o);
    const float rs = rsqrtf(sq * (1.0f / DMODEL) + 1e-5f);
    const float4 gv = *(const float4*)(g1 + l * 4);
    const float4 bv = *(const float4*)(be1 + l * 4);
    const float r0 = dx * rs * gv.x + bv.x;
    const float r1 = dy * rs * gv.y + bv.y;
    const float r2 = dz * rs * gv.z + bv.z;
    const float r3 = dw * rs * gv.w + bv.w;
    *(float4*)(of + (size_t)row * DMODEL + l * 4) = make_float4(r0, r1, r2, r3);
    uint2 pk;
    pk.x = (unsigned)f2b(r0) | ((unsigned)f2b(r1) << 16);
    pk.y = (unsigned)f2b(r2) | ((unsigned)f2b(r3) << 16);
    *(uint2*)(ob + (size_t)row * DMODEL + l * 4) = pk;
}

// ---------------------------------------------------------------------------
// Generic GEMM core: tile (MF*64 M) x (NF*16 N), BK=64 chunks, double-buffered
// LDS B with register prefetch, 1 barrier/chunk. mfma(B,A): lane q = out row,
// g*4+r = out col within each n-fragment. LDS per buffer = NF*16*128 bytes.
// ---------------------------------------------------------------------------
template <int MF, int NF>
__device__ __forceinline__ void gemm_core(
    const u16* __restrict__ A, const u16* __restrict__ Bw,
    int K, int nbase, int rowbase, u16* sB, f32x4 acc[MF][NF])
{
    const int tid = threadIdx.x, w = tid >> 6, l = tid & 63;
    const int g = l >> 4, q = l & 15;
    const u16* Arow = A + (size_t)(rowbase + w * (MF * 16) + q) * K + g * 8;

    const int sbr = tid >> 3, sseg = tid & 7;
    const int LOADS = NF / 2;            // uint4 loads per thread per chunk
    const int CHUNK = NF * 16 * 128;     // bytes per LDS buffer
    size_t bsrc[LOADS];
    int d[LOADS];
    #pragma unroll
    for (int i = 0; i < LOADS; ++i) {
        bsrc[i] = (size_t)(nbase + sbr + 32 * i) * K + sseg * 8;
        d[i] = (sbr + 32 * i) * 128 + ((sseg * 16) ^ ((sbr & 7) << 4));
    }

    {   // prologue: stage chunk 0 into buf0
        #pragma unroll
        for (int i = 0; i < LOADS; ++i) {
            const uint4 r = *(const uint4*)(Bw + bsrc[i]);
            *(uint4*)((char*)sB + d[i]) = r;
        }
    }
    const int NC = K >> 6;
    for (int c = 0; c < NC; ++c) {
        __syncthreads();
        char* sBc = (char*)sB + (c & 1) * CHUNK;
        char* sBn = (char*)sB + ((c + 1) & 1) * CHUNK;
        uint4 p[LOADS];
        if (c + 1 < NC) {
            #pragma unroll
            for (int i = 0; i < LOADS; ++i)
                p[i] = *(const uint4*)(Bw + bsrc[i] + (c + 1) * 64);
        }
        const int kk = c * 64;
        #pragma unroll
        for (int ks = 0; ks < 2; ++ks) {
            bf16x8 af[MF];
            #pragma unroll
            for (int m = 0; m < MF; ++m)
                af[m] = *(const bf16x8*)(Arow + (size_t)m * 16 * K + kk + ks * 32);
            #pragma unroll
            for (int n = 0; n < NF; ++n) {
                const int rr = n * 16 + q;
                const bf16x8 bf = *(const bf16x8*)(
                    sBc + rr * 128 + ((ks * 64 + g * 16) ^ ((rr & 7) << 4)));
                #pragma unroll
                for (int m = 0; m < MF; ++m)
                    acc[m][n] = __builtin_amdgcn_mfma_f32_16x16x32_bf16(bf, af[m], acc[m][n], 0, 0, 0);
            }
        }
        if (c + 1 < NC) {
            #pragma unroll
            for (int i = 0; i < LOADS; ++i)
                *(uint4*)(sBn + d[i]) = p[i];
        }
    }
}

// ---------------------------------------------------------------------------
// QKV GEMM (tile 128x128): head-contiguous epilogue -> Qh/Kh [BH,S,32],
// Vt [BH,32,S]. grid (64, 6).
// ---------------------------------------------------------------------------
__global__ __launch_bounds__(256) void gemm_qkv(
    const u16* __restrict__ A, const u16* __restrict__ Bw,
    const float* __restrict__ bias,
    u16* __restrict__ Qh, u16* __restrict__ Kh, u16* __restrict__ Vt)
{
    __shared__ u16 sB[2][128 * 64];
    const int tid = threadIdx.x, w = tid >> 6, l = tid & 63;
    const int g = l >> 4, q = l & 15;
    const int rowbase = blockIdx.x * 128, nbase = blockIdx.y * 128;
    f32x4 acc[2][8] = {};
    gemm_core<2, 8>(A, Bw, 256, nbase, rowbase, &sB[0][0], acc);

    #pragma unroll
    for (int m = 0; m < 2; ++m) {
        const int row = rowbase + w * 32 + m * 16 + q;
        const int s = row >> 3, b = row & 7;
        #pragma unroll
        for (int n = 0; n < 8; ++n) {
            const int col = nbase + n * 16 + g * 4;
            const float4 bv = *(const float4*)(bias + col);
            if (col < 512) {
                u16* dst = (col >= 256) ? Kh : Qh;
                const int cc = col & 255, h = cc >> 5, hd = cc & 31;
                const int bh = b * 8 + h;
                uint2 pk;
                pk.x = (unsigned)f2b(acc[m][n][0] + bv.x) | ((unsigned)f2b(acc[m][n][1] + bv.y) << 16);
                pk.y = (unsigned)f2b(acc[m][n][2] + bv.z) | ((unsigned)f2b(acc[m][n][3] + bv.w) << 16);
                *(uint2*)(dst + ((size_t)bh * S_LEN + s) * HDIM + hd) = pk;
            } else {
                const int cc = col - 512, h = cc >> 5, hd = cc & 31;
                const int bh = b * 8 + h;
                Vt[((size_t)bh * HDIM + hd + 0) * S_LEN + s] = f2b(acc[m][n][0] + bv.x);
                Vt[((size_t)bh * HDIM + hd + 1) * S_LEN + s] = f2b(acc[m][n][1] + bv.y);
                Vt[((size_t)bh * HDIM + hd + 2) * S_LEN + s] = f2b(acc[m][n][2] + bv.z);
                Vt[((size_t)bh * HDIM + hd + 3) * S_LEN + s] = f2b(acc[m][n][3] + bv.w);
            }
        }
    }
}

// ---------------------------------------------------------------------------
// FFN1 (tile 128x128): relu(yb@W1^T+b1) -> hb bf16. grid (64, 8).
// ---------------------------------------------------------------------------
__global__ __launch_bounds__(256) void gemm_ffn1(
    const u16* __restrict__ A, const u16* __restrict__ Bw,
    const float* __restrict__ bias, u16* __restrict__ outb)
{
    __shared__ u16 sB[2][128 * 64];
    const int tid = threadIdx.x, w = tid >> 6, l = tid & 63;
    const int g = l >> 4, q = l & 15;
    const int rowbase = blockIdx.x * 128, nbase = blockIdx.y * 128;
    f32x4 acc[2][8] = {};
    gemm_core<2, 8>(A, Bw, 256, nbase, rowbase, &sB[0][0], acc);

    #pragma unroll
    for (int m = 0; m < 2; ++m) {
        const int row = rowbase + w * 32 + m * 16 + q;
        #pragma unroll
        for (int n = 0; n < 8; ++n) {
            const int col = nbase + n * 16 + g * 4;
            const float4 bv = *(const float4*)(bias + col);
            const float v0 = fmaxf(acc[m][n][0] + bv.x, 0.f);
            const float v1 = fmaxf(acc[m][n][1] + bv.y, 0.f);
            const float v2 = fmaxf(acc[m][n][2] + bv.z, 0.f);
            const float v3 = fmaxf(acc[m][n][3] + bv.w, 0.f);
            uint2 pk;
            pk.x = (unsigned)f2b(v0) | ((unsigned)f2b(v1) << 16);
            pk.y = (unsigned)f2b(v2) | ((unsigned)f2b(v3) << 16);
            *(uint2*)(outb + (size_t)row * DFF + col) = pk;
        }
    }
}

// ---------------------------------------------------------------------------
// FFN2 (tile 128x64): hb@W2^T + b2 + resid(yf) -> f32 out. grid (64, 4).
// ---------------------------------------------------------------------------
__global__ __launch_bounds__(256) void gemm_ffn2(
    const u16* __restrict__ A, const u16* __restrict__ Bw,
    const float* __restrict__ bias, const float* __restrict__ resid,
    float* __restrict__ outf)
{
    __shared__ u16 sB[2][64 * 64];
    const int tid = threadIdx.x, w = tid >> 6, l = tid & 63;
    const int g = l >> 4, q = l & 15;
    const int rowbase = blockIdx.x * 128, nbase = blockIdx.y * 64;
    f32x4 acc[2][4] = {};
    gemm_core<2, 4>(A, Bw, 1024, nbase, rowbase, &sB[0][0], acc);

    #pragma unroll
    for (int m = 0; m < 2; ++m) {
        const int row = rowbase + w * 32 + m * 16 + q;
        #pragma unroll
        for (int n = 0; n < 4; ++n) {
            const int col = nbase + n * 16 + g * 4;
            const float4 bv = *(const float4*)(bias + col);
            const float4 rv = *(const float4*)(resid + (size_t)row * DMODEL + col);
            *(float4*)(outf + (size_t)row * DMODEL + col) = make_float4(
                acc[m][n][0] + bv.x + rv.x, acc[m][n][1] + bv.y + rv.y,
                acc[m][n][2] + bv.z + rv.z, acc[m][n][3] + bv.w + rv.w);
        }
    }
}

// ---------------------------------------------------------------------------
// Flash attention: LDS-staged K/V in MFMA-fragment order (conflict-free b128,
// double-buffered, async-split), lane-local softmax, pipelined nontemporal
// bias stream. grid (S/64, B*H), 256 thr (4 waves x 16 q-rows).
// ---------------------------------------------------------------------------
__global__ __launch_bounds__(256) void attn_kernel(
    const u16* __restrict__ Qh, const u16* __restrict__ Kh,
    const u16* __restrict__ Vt, const float* __restrict__ bias,
    u16* __restrict__ ctx)
{
    __shared__ u16 sK[2][64 * 32];
    __shared__ u16 sV[2][32 * 64];
    __shared__ u16 sP[4][16 * 64];
    const int tid = threadIdx.x, w = tid >> 6, l = tid & 63;
    const int g = l >> 4, q = l & 15;
    const int bh = blockIdx.y, b = bh >> 3, h = bh & 7;
    const int qbase = blockIdx.x * 64 + w * 16;
    const int qrow = qbase + q;

    const bf16x8 qf = *(const bf16x8*)(Qh + ((size_t)bh * S_LEN + qrow) * HDIM + g * 8);
    const float* brow = bias + ((size_t)bh * S_LEN + qrow) * S_LEN;
    u16* Pw = sP[w];
    const int swz = (q & 7) << 4;

    const u16* KsrcBase = Kh + ((size_t)bh * S_LEN + w * 16 + q) * HDIM + g * 8;
    const u16* VsrcBase = Vt + ((size_t)bh * HDIM + (w & 1) * 16 + q) * S_LEN
                             + (w >> 1) * 32 + g * 8;
    u16* KdstA = &sK[0][tid * 8]; u16* KdstB = &sK[1][tid * 8];
    u16* VdstA = &sV[0][tid * 8]; u16* VdstB = &sV[1][tid * 8];

    f32x4 ctxa[2] = {{0,0,0,0},{0,0,0,0}};
    float m = -1e30f, lsum = 0.f;

    auto loadB = [&](int kt, f32x4* bv) {
        #pragma unroll
        for (int n = 0; n < 4; ++n)
            bv[n] = __builtin_nontemporal_load(
                (const f32x4*)(brow + kt * 64 + n * 16 + g * 4));
    };

    auto proc = [&](int buf, const f32x4* bv) {
        f32x4 sc[4];
        #pragma unroll
        for (int n = 0; n < 4; ++n) {
            const bf16x8 kf = *(const bf16x8*)(&sK[buf][(n * 64 + l) * 8]);
            f32x4 z = {0, 0, 0, 0};
            sc[n] = __builtin_amdgcn_mfma_f32_16x16x32_bf16(kf, qf, z, 0, 0, 0);
        }
        #pragma unroll
        for (int n = 0; n < 4; ++n)
            #pragma unroll
            for (int r = 0; r < 4; ++r) sc[n][r] += bv[n][r];

        float mx = sc[0][0];
        #pragma unroll
        for (int n = 0; n < 4; ++n)
            #pragma unroll
            for (int r = 0; r < 4; ++r) mx = fmaxf(mx, sc[n][r]);
        mx = fmaxf(mx, __shfl_xor(mx, 16));
        mx = fmaxf(mx, __shfl_xor(mx, 32));
        const float mn = fmaxf(m, mx);
        const float corr = __expf(m - mn);
        float su = 0.f;
        u16 pb[16];
        #pragma unroll
        for (int n = 0; n < 4; ++n)
            #pragma unroll
            for (int r = 0; r < 4; ++r) {
                const float pv = __expf(sc[n][r] - mn);
                su += pv;
                pb[n * 4 + r] = f2b(pv);
            }
        su += __shfl_xor(su, 16);
        su += __shfl_xor(su, 32);
        lsum = lsum * corr + su;
        m = mn;
        #pragma unroll
        for (int jg = 0; jg < 2; ++jg)
            #pragma unroll
            for (int r = 0; r < 4; ++r) ctxa[jg][r] *= corr;

        #pragma unroll
        for (int n = 0; n < 4; ++n) {
            uint2 pk;
            pk.x = (unsigned)pb[n * 4] | ((unsigned)pb[n * 4 + 1] << 16);
            pk.y = (unsigned)pb[n * 4 + 2] | ((unsigned)pb[n * 4 + 3] << 16);
            *(uint2*)((char*)Pw + q * 128 + ((n * 32 + g * 8) ^ swz)) = pk;
        }

        #pragma unroll
        for (int ks = 0; ks < 2; ++ks) {
            const bf16x8 pf = *(const bf16x8*)((char*)Pw + q * 128 + ((ks * 64 + g * 16) ^ swz));
            #pragma unroll
            for (int jg = 0; jg < 2; ++jg) {
                const bf16x8 vf = *(const bf16x8*)(&sV[buf][((ks * 2 + jg) * 64 + l) * 8]);
                ctxa[jg] = __builtin_amdgcn_mfma_f32_16x16x32_bf16(vf, pf, ctxa[jg], 0, 0, 0);
            }
        }
    };

    f32x4 bv0[4], bv1[4];
    {
        const uint4 kr = *(const uint4*)(KsrcBase);
        const uint4 vr = *(const uint4*)(VsrcBase);
        *(uint4*)KdstA = kr;
        *(uint4*)VdstA = vr;
        loadB(0, bv0);
    }
    __syncthreads();

    for (int kt = 0; kt < 16; kt += 2) {
        {
            uint4 kr, vr;
            kr = *(const uint4*)(KsrcBase + (size_t)(kt + 1) * 64 * HDIM);
            vr = *(const uint4*)(VsrcBase + (size_t)(kt + 1) * 64);
            loadB(kt + 1, bv1);
            proc(0, bv0);
            *(uint4*)KdstB = kr;
            *(uint4*)VdstB = vr;
        }
        __syncthreads();
        {
            uint4 kr, vr;
            if (kt + 2 < 16) {
                kr = *(const uint4*)(KsrcBase + (size_t)(kt + 2) * 64 * HDIM);
                vr = *(const uint4*)(VsrcBase + (size_t)(kt + 2) * 64);
                loadB(kt + 2, bv0);
            }
            proc(1, bv1);
            if (kt + 2 < 16) {
                *(uint4*)KdstA = kr;
                *(uint4*)VdstA = vr;
            }
        }
        __syncthreads();
    }

    const float inv = 1.0f / lsum;
    #pragma unroll
    for (int jg = 0; jg < 2; ++jg) {
        uint2 pk;
        pk.x = (unsigned)f2b(ctxa[jg][0] * inv) | ((unsigned)f2b(ctxa[jg][1] * inv) << 16);
        pk.y = (unsigned)f2b(ctxa[jg][2] * inv) | ((unsigned)f2b(ctxa[jg][3] * inv) << 16);
        *(uint2*)(ctx + ((size_t)qrow * 8 + b) * DMODEL + h * 32 + jg * 16 + g * 4) = pk;
    }
}

// ---------------------------------------------------------------------------
// Fused out-proj + residual(xf) + LayerNorm2 -> yf (f32), yb (bf16).
// 32 rows/block (2 row-frags/wave), grid 256.
// ---------------------------------------------------------------------------
__global__ __launch_bounds__(256) void oproj_ln(
    const u16* __restrict__ ctx, const u16* __restrict__ wob,
    const float* __restrict__ ob, const float* __restrict__ xf,
    const float* __restrict__ g2, const float* __restrict__ be2,
    float* __restrict__ yf, u16* __restrict__ yb)
{
    __shared__ float s1[4][32], s2[4][32];
    const int tid = threadIdx.x, wv = tid >> 6, l = tid & 63;
    const int g = l >> 4, q = l & 15;
    const int rowbase = blockIdx.x * 32;
    f32x4 acc[2][4] = {};
    const u16* Arow = ctx + (size_t)(rowbase + q) * 256 + g * 8;
    const u16* Brow = wob + (size_t)(wv * 64 + q) * 256 + g * 8;

    #pragma unroll 2
    for (int kk = 0; kk < 256; kk += 32) {
        bf16x8 af[2];
        #pragma unroll
        for (int m = 0; m < 2; ++m)
            af[m] = *(const bf16x8*)(Arow + (size_t)m * 16 * 256 + kk);
        #pragma unroll
        for (int n = 0; n < 4; ++n) {
            const bf16x8 bf = *(const bf16x8*)(Brow + (size_t)n * 16 * 256 + kk);
            #pragma unroll
            for (int m = 0; m < 2; ++m)
                acc[m][n] = __builtin_amdgcn_mfma_f32_16x16x32_bf16(bf, af[m], acc[m][n], 0, 0, 0);
        }
    }

    float sum[2] = {0.f, 0.f};
    #pragma unroll
    for (int m = 0; m < 2; ++m) {
        const int row = rowbase + m * 16 + q;
        #pragma unroll
        for (int n = 0; n < 4; ++n) {
            const int col = wv * 64 + n * 16 + g * 4;
            const float4 bv = *(const float4*)(ob + col);
            const float4 rv = *(const float4*)(xf + (size_t)row * 256 + col);
            acc[m][n][0] += bv.x + rv.x; acc[m][n][1] += bv.y + rv.y;
            acc[m][n][2] += bv.z + rv.z; acc[m][n][3] += bv.w + rv.w;
            sum[m] += acc[m][n][0] + acc[m][n][1] + acc[m][n][2] + acc[m][n][3];
        }
        sum[m] += __shfl_xor(sum[m], 16);
        sum[m] += __shfl_xor(sum[m], 32);
    }
    if (l < 16) { s1[wv][q] = sum[0]; s1[wv][16 + q] = sum[1]; }
    __syncthreads();
    float mu[2], rs[2];
    #pragma unroll
    for (int m = 0; m < 2; ++m) {
        const int lr = m * 16 + q;
        mu[m] = (s1[0][lr] + s1[1][lr] + s1[2][lr] + s1[3][lr]) * (1.0f / 256);
    }
    float sq[2] = {0.f, 0.f};
    #pragma unroll
    for (int m = 0; m < 2; ++m) {
        #pragma unroll
        for (int n = 0; n < 4; ++n)
            #pragma unroll
            for (int r = 0; r < 4; ++r) {
                const float d = acc[m][n][r] - mu[m];
                sq[m] += d * d;
            }
        sq[m] += __shfl_xor(sq[m], 16);
        sq[m] += __shfl_xor(sq[m], 32);
    }
    if (l < 16) { s2[wv][q] = sq[0]; s2[wv][16 + q] = sq[1]; }
    __syncthreads();
    #pragma unroll
    for (int m = 0; m < 2; ++m) {
        const int lr = m * 16 + q;
        rs[m] = rsqrtf((s2[0][lr] + s2[1][lr] + s2[2][lr] + s2[3][lr]) * (1.0f / 256) + 1e-5f);
    }

    #pragma unroll
    for (int m = 0; m < 2; ++m) {
        const int row = rowbase + m * 16 + q;
        #pragma unroll
        for (int n = 0; n < 4; ++n) {
            const int col = wv * 64 + n * 16 + g * 4;
            const float4 gv = *(const float4*)(g2 + col);
            const float4 b2 = *(const float4*)(be2 + col);
            const float y0 = (acc[m][n][0] - mu[m]) * rs[m] * gv.x + b2.x;
            const float y1 = (acc[m][n][1] - mu[m]) * rs[m] * gv.y + b2.y;
            const float y2 = (acc[m][n][2] - mu[m]) * rs[m] * gv.z + b2.z;
            const float y3 = (acc[m][n][3] - mu[m]) * rs[m] * gv.w + b2.w;
            *(float4*)(yf + (size_t)row * 256 + col) = make_float4(y0, y1, y2, y3);
            uint2 pk;
            pk.x = (unsigned)f2b(y0) | ((unsigned)f2b(y1) << 16);
            pk.y = (unsigned)f2b(y2) | ((unsigned)f2b(y3) << 16);
            *(uint2*)(yb + (size_t)row * 256 + col) = pk;
        }
    }
}

// ---------------------------------------------------------------------------
extern "C" void kernel_launch(void* const* d_in, const int* in_sizes, int n_in,
                              void* d_out, int out_size, void* d_ws, size_t ws_size,
                              hipStream_t stream)
{
    const float* src  = (const float*)d_in[0];
    const float* bias = (const float*)d_in[1];
    const float* ipw  = (const float*)d_in[2];
    const float* ipb  = (const float*)d_in[3];
    const float* outw = (const float*)d_in[4];
    const float* outb = (const float*)d_in[5];
    const float* w1   = (const float*)d_in[6];
    const float* b1   = (const float*)d_in[7];
    const float* w2   = (const float*)d_in[8];
    const float* b2   = (const float*)d_in[9];
    const float* g1   = (const float*)d_in[10];
    const float* be1  = (const float*)d_in[11];
    const float* g2   = (const float*)d_in[12];
    const float* be2  = (const float*)d_in[13];

    char* p = (char*)d_ws;
    auto alloc = [&](size_t bytes) -> void* {
        void* r = (void*)p;
        p += (bytes + 255) & ~(size_t)255;
        return r;
    };
    float* xf   = (float*)alloc((size_t)NROWS * DMODEL * 4);
    u16*   xb   = (u16*)  alloc((size_t)NROWS * DMODEL * 2);
    u16*   Qh   = (u16*)  alloc((size_t)64 * S_LEN * HDIM * 2);
    u16*   Kb   = (u16*)  alloc((size_t)64 * S_LEN * HDIM * 2);
    u16*   Vt   = (u16*)  alloc((size_t)64 * S_LEN * HDIM * 2);
    u16*   ctx  = (u16*)  alloc((size_t)NROWS * DMODEL * 2);
    float* yf   = (float*)alloc((size_t)NROWS * DMODEL * 4);
    u16*   yb   = (u16*)  alloc((size_t)NROWS * DMODEL * 2);
    u16*   hb   = (u16*)  alloc((size_t)NROWS * DFF * 2);
    u16*   wqkv = (u16*)  alloc((size_t)768 * 256 * 2);
    u16*   wob  = (u16*)  alloc((size_t)256 * 256 * 2);
    u16*   w1b  = (u16*)  alloc((size_t)1024 * 256 * 2);
    u16*   w2b  = (u16*)  alloc((size_t)256 * 1024 * 2);
    float* bq   = (float*)alloc(768 * 4);

    prep_kernel<<<2816, 256, 0, stream>>>(src, g1, be1, xf, xb,
                                          ipw, outw, w1, w2, ipb,
                                          wqkv, wob, w1b, w2b, bq);
    gemm_qkv<<<dim3(64, 6), 256, 0, stream>>>(xb, wqkv, bq, Qh, Kb, Vt);
    attn_kernel<<<dim3(16, 64), 256, 0, stream>>>(Qh, Kb, Vt, bias, ctx);
    oproj_ln<<<256, 256, 0, stream>>>(ctx, wob, outb, xf, g2, be2, yf, yb);
    gemm_ffn1<<<dim3(64, 8), 256, 0, stream>>>(yb, w1b, b1, hb);
    gemm_ffn2<<<dim3(64, 4), 256, 0, stream>>>(hb, w2b, b2, yf, (float*)d_out);
}

// Round 9
// 152.461 us; speedup vs baseline: 1.0424x; 1.0314x over previous
//
#include <hip/hip_runtime.h>
#include <hip/hip_bf16.h>
#include <cstdint>

typedef unsigned short u16;
typedef __attribute__((ext_vector_type(8))) short bf16x8;
typedef __attribute__((ext_vector_type(4))) float f32x4;

#define S_LEN 1024
#define BATCH 8
#define DMODEL 256
#define NHEAD 8
#define HDIM 32
#define DFF 1024
#define NROWS (S_LEN * BATCH)   // 8192

static __device__ __forceinline__ u16 f2b(float f) {
    union { float f; unsigned u; } x{f};
    unsigned r = (x.u + 0x7fffu + ((x.u >> 16) & 1u)) >> 16;
    return (u16)r;
}
static __device__ __forceinline__ float b2f(unsigned h) {
    union { unsigned u; float f; } x{h << 16};
    return x.f;
}

// ---------------------------------------------------------------------------
// Fused prep: blocks [0,2048) = LayerNorm1 (4 rows/block) -> xb bf16 only;
//             blocks [2048,2816) = weight f32->bf16 convert (q-scale folded).
// ---------------------------------------------------------------------------
__global__ __launch_bounds__(256) void prep_kernel(
    const float* __restrict__ in, const float* __restrict__ g1,
    const float* __restrict__ be1, u16* __restrict__ ob,
    const float* __restrict__ ipw, const float* __restrict__ outw,
    const float* __restrict__ w1, const float* __restrict__ w2,
    const float* __restrict__ ipb,
    u16* __restrict__ wqkv, u16* __restrict__ wout,
    u16* __restrict__ w1b, u16* __restrict__ w2b, float* __restrict__ bq)
{
    const float s = 0.17677669529663689f; // 1/sqrt(32)
    if (blockIdx.x >= 2048) {
        const int i4 = ((int)blockIdx.x - 2048) * 1024 + threadIdx.x * 4;
        const float* src; u16* dst; int off; float sc = 1.0f;
        if (i4 < 196608)      { src = ipw;  dst = wqkv; off = 0;      if (i4 < 65536) sc = s; }
        else if (i4 < 262144) { src = outw; dst = wout; off = 196608; }
        else if (i4 < 524288) { src = w1;   dst = w1b;  off = 262144; }
        else                  { src = w2;   dst = w2b;  off = 524288; }
        const float4 v = *(const float4*)(src + i4 - off);
        uint2 pk;
        pk.x = (unsigned)f2b(v.x * sc) | ((unsigned)f2b(v.y * sc) << 16);
        pk.y = (unsigned)f2b(v.z * sc) | ((unsigned)f2b(v.w * sc) << 16);
        *(uint2*)(dst + i4 - off) = pk;
        if (i4 < 768) {
            const float4 b = *(const float4*)(ipb + i4);
            const float bs = (i4 < 256) ? s : 1.0f;
            *(float4*)(bq + i4) = make_float4(b.x * bs, b.y * bs, b.z * bs, b.w * bs);
        }
        return;
    }
    const int w = threadIdx.x >> 6, l = threadIdx.x & 63;
    const int row = blockIdx.x * 4 + w;
    const float4 v = *(const float4*)(in + (size_t)row * DMODEL + l * 4);
    float s0 = v.x + v.y + v.z + v.w;
    #pragma unroll
    for (int o = 32; o; o >>= 1) s0 += __shfl_xor(s0, o);
    const float mu = s0 * (1.0f / DMODEL);
    const float dx = v.x - mu, dy = v.y - mu, dz = v.z - mu, dw = v.w - mu;
    float sq = dx * dx + dy * dy + dz * dz + dw * dw;
    #pragma unroll
    for (int o = 32; o; o >>= 1) sq += __shfl_xor(sq, o);
    const float rs = rsqrtf(sq * (1.0f / DMODEL) + 1e-5f);
    const float4 gv = *(const float4*)(g1 + l * 4);
    const float4 bv = *(const float4*)(be1 + l * 4);
    const float r0 = dx * rs * gv.x + bv.x;
    const float r1 = dy * rs * gv.y + bv.y;
    const float r2 = dz * rs * gv.z + bv.z;
    const float r3 = dw * rs * gv.w + bv.w;
    uint2 pk;
    pk.x = (unsigned)f2b(r0) | ((unsigned)f2b(r1) << 16);
    pk.y = (unsigned)f2b(r2) | ((unsigned)f2b(r3) << 16);
    *(uint2*)(ob + (size_t)row * DMODEL + l * 4) = pk;
}

// ---------------------------------------------------------------------------
// Generic GEMM core: tile (MF*64 M) x (NF*16 N), BK=64 chunks, double-buffered
// LDS B with register prefetch, 1 barrier/chunk. mfma(B,A): lane q = out row,
// g*4+r = out col within each n-fragment.
// ---------------------------------------------------------------------------
template <int MF, int NF>
__device__ __forceinline__ void gemm_core(
    const u16* __restrict__ A, const u16* __restrict__ Bw,
    int K, int nbase, int rowbase, u16* sB, f32x4 acc[MF][NF])
{
    const int tid = threadIdx.x, w = tid >> 6, l = tid & 63;
    const int g = l >> 4, q = l & 15;
    const u16* Arow = A + (size_t)(rowbase + w * (MF * 16) + q) * K + g * 8;

    const int sbr = tid >> 3, sseg = tid & 7;
    const int LOADS = NF / 2;
    const int CHUNK = NF * 16 * 128;
    size_t bsrc[LOADS];
    int d[LOADS];
    #pragma unroll
    for (int i = 0; i < LOADS; ++i) {
        bsrc[i] = (size_t)(nbase + sbr + 32 * i) * K + sseg * 8;
        d[i] = (sbr + 32 * i) * 128 + ((sseg * 16) ^ ((sbr & 7) << 4));
    }

    {
        #pragma unroll
        for (int i = 0; i < LOADS; ++i) {
            const uint4 r = *(const uint4*)(Bw + bsrc[i]);
            *(uint4*)((char*)sB + d[i]) = r;
        }
    }
    const int NC = K >> 6;
    for (int c = 0; c < NC; ++c) {
        __syncthreads();
        char* sBc = (char*)sB + (c & 1) * CHUNK;
        char* sBn = (char*)sB + ((c + 1) & 1) * CHUNK;
        uint4 p[LOADS];
        if (c + 1 < NC) {
            #pragma unroll
            for (int i = 0; i < LOADS; ++i)
                p[i] = *(const uint4*)(Bw + bsrc[i] + (c + 1) * 64);
        }
        const int kk = c * 64;
        #pragma unroll
        for (int ks = 0; ks < 2; ++ks) {
            bf16x8 af[MF];
            #pragma unroll
            for (int m = 0; m < MF; ++m)
                af[m] = *(const bf16x8*)(Arow + (size_t)m * 16 * K + kk + ks * 32);
            #pragma unroll
            for (int n = 0; n < NF; ++n) {
                const int rr = n * 16 + q;
                const bf16x8 bf = *(const bf16x8*)(
                    sBc + rr * 128 + ((ks * 64 + g * 16) ^ ((rr & 7) << 4)));
                #pragma unroll
                for (int m = 0; m < MF; ++m)
                    acc[m][n] = __builtin_amdgcn_mfma_f32_16x16x32_bf16(bf, af[m], acc[m][n], 0, 0, 0);
            }
        }
        if (c + 1 < NC) {
            #pragma unroll
            for (int i = 0; i < LOADS; ++i)
                *(uint4*)(sBn + d[i]) = p[i];
        }
    }
}

// ---------------------------------------------------------------------------
// QKV GEMM (tile 128x128): head-contiguous epilogue -> Qh/Kh [BH,S,32],
// Vt [BH,32,S]. grid (64, 6).
// ---------------------------------------------------------------------------
__global__ __launch_bounds__(256) void gemm_qkv(
    const u16* __restrict__ A, const u16* __restrict__ Bw,
    const float* __restrict__ bias,
    u16* __restrict__ Qh, u16* __restrict__ Kh, u16* __restrict__ Vt)
{
    __shared__ u16 sB[2][128 * 64];
    const int tid = threadIdx.x, w = tid >> 6, l = tid & 63;
    const int g = l >> 4, q = l & 15;
    const int rowbase = blockIdx.x * 128, nbase = blockIdx.y * 128;
    f32x4 acc[2][8] = {};
    gemm_core<2, 8>(A, Bw, 256, nbase, rowbase, &sB[0][0], acc);

    #pragma unroll
    for (int m = 0; m < 2; ++m) {
        const int row = rowbase + w * 32 + m * 16 + q;
        const int s = row >> 3, b = row & 7;
        #pragma unroll
        for (int n = 0; n < 8; ++n) {
            const int col = nbase + n * 16 + g * 4;
            const float4 bv = *(const float4*)(bias + col);
            if (col < 512) {
                u16* dst = (col >= 256) ? Kh : Qh;
                const int cc = col & 255, h = cc >> 5, hd = cc & 31;
                const int bh = b * 8 + h;
                uint2 pk;
                pk.x = (unsigned)f2b(acc[m][n][0] + bv.x) | ((unsigned)f2b(acc[m][n][1] + bv.y) << 16);
                pk.y = (unsigned)f2b(acc[m][n][2] + bv.z) | ((unsigned)f2b(acc[m][n][3] + bv.w) << 16);
                *(uint2*)(dst + ((size_t)bh * S_LEN + s) * HDIM + hd) = pk;
            } else {
                const int cc = col - 512, h = cc >> 5, hd = cc & 31;
                const int bh = b * 8 + h;
                Vt[((size_t)bh * HDIM + hd + 0) * S_LEN + s] = f2b(acc[m][n][0] + bv.x);
                Vt[((size_t)bh * HDIM + hd + 1) * S_LEN + s] = f2b(acc[m][n][1] + bv.y);
                Vt[((size_t)bh * HDIM + hd + 2) * S_LEN + s] = f2b(acc[m][n][2] + bv.z);
                Vt[((size_t)bh * HDIM + hd + 3) * S_LEN + s] = f2b(acc[m][n][3] + bv.w);
            }
        }
    }
}

// ---------------------------------------------------------------------------
// FFN1 (tile 128x128): relu(yb@W1^T+b1) -> hb bf16. grid (64, 8).
// ---------------------------------------------------------------------------
__global__ __launch_bounds__(256) void gemm_ffn1(
    const u16* __restrict__ A, const u16* __restrict__ Bw,
    const float* __restrict__ bias, u16* __restrict__ outb)
{
    __shared__ u16 sB[2][128 * 64];
    const int tid = threadIdx.x, w = tid >> 6, l = tid & 63;
    const int g = l >> 4, q = l & 15;
    const int rowbase = blockIdx.x * 128, nbase = blockIdx.y * 128;
    f32x4 acc[2][8] = {};
    gemm_core<2, 8>(A, Bw, 256, nbase, rowbase, &sB[0][0], acc);

    #pragma unroll
    for (int m = 0; m < 2; ++m) {
        const int row = rowbase + w * 32 + m * 16 + q;
        #pragma unroll
        for (int n = 0; n < 8; ++n) {
            const int col = nbase + n * 16 + g * 4;
            const float4 bv = *(const float4*)(bias + col);
            const float v0 = fmaxf(acc[m][n][0] + bv.x, 0.f);
            const float v1 = fmaxf(acc[m][n][1] + bv.y, 0.f);
            const float v2 = fmaxf(acc[m][n][2] + bv.z, 0.f);
            const float v3 = fmaxf(acc[m][n][3] + bv.w, 0.f);
            uint2 pk;
            pk.x = (unsigned)f2b(v0) | ((unsigned)f2b(v1) << 16);
            pk.y = (unsigned)f2b(v2) | ((unsigned)f2b(v3) << 16);
            *(uint2*)(outb + (size_t)row * DFF + col) = pk;
        }
    }
}

// ---------------------------------------------------------------------------
// FFN2 (tile 128x64): hb@W2^T + b2 + resid(yb bf16) -> f32 out. grid (64, 4).
// ---------------------------------------------------------------------------
__global__ __launch_bounds__(256) void gemm_ffn2(
    const u16* __restrict__ A, const u16* __restrict__ Bw,
    const float* __restrict__ bias, const u16* __restrict__ resid,
    float* __restrict__ outf)
{
    __shared__ u16 sB[2][64 * 64];
    const int tid = threadIdx.x, w = tid >> 6, l = tid & 63;
    const int g = l >> 4, q = l & 15;
    const int rowbase = blockIdx.x * 128, nbase = blockIdx.y * 64;
    f32x4 acc[2][4] = {};
    gemm_core<2, 4>(A, Bw, 1024, nbase, rowbase, &sB[0][0], acc);

    #pragma unroll
    for (int m = 0; m < 2; ++m) {
        const int row = rowbase + w * 32 + m * 16 + q;
        #pragma unroll
        for (int n = 0; n < 4; ++n) {
            const int col = nbase + n * 16 + g * 4;
            const float4 bv = *(const float4*)(bias + col);
            const uint2 rp = *(const uint2*)(resid + (size_t)row * DMODEL + col);
            *(float4*)(outf + (size_t)row * DMODEL + col) = make_float4(
                acc[m][n][0] + bv.x + b2f(rp.x & 0xffffu),
                acc[m][n][1] + bv.y + b2f(rp.x >> 16),
                acc[m][n][2] + bv.z + b2f(rp.y & 0xffffu),
                acc[m][n][3] + bv.w + b2f(rp.y >> 16));
        }
    }
}

// ---------------------------------------------------------------------------
// Flash attention. grid (B*H, S/64) — bh is blockIdx.x so all 16 q-blocks of
// one head land on one XCD (linear id % 8 == bh % 8): K/V stay L2-local.
// LDS-staged K/V in fragment order, double-buffered; lane-local softmax;
// pipelined nontemporal bias stream. 256 thr (4 waves x 16 q-rows).
// ---------------------------------------------------------------------------
__global__ __launch_bounds__(256) void attn_kernel(
    const u16* __restrict__ Qh, const u16* __restrict__ Kh,
    const u16* __restrict__ Vt, const float* __restrict__ bias,
    u16* __restrict__ ctx)
{
    __shared__ u16 sK[2][64 * 32];
    __shared__ u16 sV[2][32 * 64];
    __shared__ u16 sP[4][16 * 64];
    const int tid = threadIdx.x, w = tid >> 6, l = tid & 63;
    const int g = l >> 4, q = l & 15;
    const int bh = blockIdx.x, b = bh >> 3, h = bh & 7;
    const int qbase = blockIdx.y * 64 + w * 16;
    const int qrow = qbase + q;

    const bf16x8 qf = *(const bf16x8*)(Qh + ((size_t)bh * S_LEN + qrow) * HDIM + g * 8);
    const float* brow = bias + ((size_t)bh * S_LEN + qrow) * S_LEN;
    u16* Pw = sP[w];
    const int swz = (q & 7) << 4;

    const u16* KsrcBase = Kh + ((size_t)bh * S_LEN + w * 16 + q) * HDIM + g * 8;
    const u16* VsrcBase = Vt + ((size_t)bh * HDIM + (w & 1) * 16 + q) * S_LEN
                             + (w >> 1) * 32 + g * 8;
    u16* KdstA = &sK[0][tid * 8]; u16* KdstB = &sK[1][tid * 8];
    u16* VdstA = &sV[0][tid * 8]; u16* VdstB = &sV[1][tid * 8];

    f32x4 ctxa[2] = {{0,0,0,0},{0,0,0,0}};
    float m = -1e30f, lsum = 0.f;

    auto loadB = [&](int kt, f32x4* bv) {
        #pragma unroll
        for (int n = 0; n < 4; ++n)
            bv[n] = __builtin_nontemporal_load(
                (const f32x4*)(brow + kt * 64 + n * 16 + g * 4));
    };

    auto proc = [&](int buf, const f32x4* bv) {
        f32x4 sc[4];
        #pragma unroll
        for (int n = 0; n < 4; ++n) {
            const bf16x8 kf = *(const bf16x8*)(&sK[buf][(n * 64 + l) * 8]);
            f32x4 z = {0, 0, 0, 0};
            sc[n] = __builtin_amdgcn_mfma_f32_16x16x32_bf16(kf, qf, z, 0, 0, 0);
        }
        #pragma unroll
        for (int n = 0; n < 4; ++n)
            #pragma unroll
            for (int r = 0; r < 4; ++r) sc[n][r] += bv[n][r];

        float mx = sc[0][0];
        #pragma unroll
        for (int n = 0; n < 4; ++n)
            #pragma unroll
            for (int r = 0; r < 4; ++r) mx = fmaxf(mx, sc[n][r]);
        mx = fmaxf(mx, __shfl_xor(mx, 16));
        mx = fmaxf(mx, __shfl_xor(mx, 32));
        const float mn = fmaxf(m, mx);
        const float corr = __expf(m - mn);
        float su = 0.f;
        u16 pb[16];
        #pragma unroll
        for (int n = 0; n < 4; ++n)
            #pragma unroll
            for (int r = 0; r < 4; ++r) {
                const float pv = __expf(sc[n][r] - mn);
                su += pv;
                pb[n * 4 + r] = f2b(pv);
            }
        su += __shfl_xor(su, 16);
        su += __shfl_xor(su, 32);
        lsum = lsum * corr + su;
        m = mn;
        #pragma unroll
        for (int jg = 0; jg < 2; ++jg)
            #pragma unroll
            for (int r = 0; r < 4; ++r) ctxa[jg][r] *= corr;

        #pragma unroll
        for (int n = 0; n < 4; ++n) {
            uint2 pk;
            pk.x = (unsigned)pb[n * 4] | ((unsigned)pb[n * 4 + 1] << 16);
            pk.y = (unsigned)pb[n * 4 + 2] | ((unsigned)pb[n * 4 + 3] << 16);
            *(uint2*)((char*)Pw + q * 128 + ((n * 32 + g * 8) ^ swz)) = pk;
        }

        #pragma unroll
        for (int ks = 0; ks < 2; ++ks) {
            const bf16x8 pf = *(const bf16x8*)((char*)Pw + q * 128 + ((ks * 64 + g * 16) ^ swz));
            #pragma unroll
            for (int jg = 0; jg < 2; ++jg) {
                const bf16x8 vf = *(const bf16x8*)(&sV[buf][((ks * 2 + jg) * 64 + l) * 8]);
                ctxa[jg] = __builtin_amdgcn_mfma_f32_16x16x32_bf16(vf, pf, ctxa[jg], 0, 0, 0);
            }
        }
    };

    f32x4 bv0[4], bv1[4];
    {
        const uint4 kr = *(const uint4*)(KsrcBase);
        const uint4 vr = *(const uint4*)(VsrcBase);
        *(uint4*)KdstA = kr;
        *(uint4*)VdstA = vr;
        loadB(0, bv0);
    }
    __syncthreads();

    for (int kt = 0; kt < 16; kt += 2) {
        {
            uint4 kr, vr;
            kr = *(const uint4*)(KsrcBase + (size_t)(kt + 1) * 64 * HDIM);
            vr = *(const uint4*)(VsrcBase + (size_t)(kt + 1) * 64);
            loadB(kt + 1, bv1);
            proc(0, bv0);
            *(uint4*)KdstB = kr;
            *(uint4*)VdstB = vr;
        }
        __syncthreads();
        {
            uint4 kr, vr;
            if (kt + 2 < 16) {
                kr = *(const uint4*)(KsrcBase + (size_t)(kt + 2) * 64 * HDIM);
                vr = *(const uint4*)(VsrcBase + (size_t)(kt + 2) * 64);
                loadB(kt + 2, bv0);
            }
            proc(1, bv1);
            if (kt + 2 < 16) {
                *(uint4*)KdstA = kr;
                *(uint4*)VdstA = vr;
            }
        }
        __syncthreads();
    }

    const float inv = 1.0f / lsum;
    #pragma unroll
    for (int jg = 0; jg < 2; ++jg) {
        uint2 pk;
        pk.x = (unsigned)f2b(ctxa[jg][0] * inv) | ((unsigned)f2b(ctxa[jg][1] * inv) << 16);
        pk.y = (unsigned)f2b(ctxa[jg][2] * inv) | ((unsigned)f2b(ctxa[jg][3] * inv) << 16);
        *(uint2*)(ctx + ((size_t)qrow * 8 + b) * DMODEL + h * 32 + jg * 16 + g * 4) = pk;
    }
}

// ---------------------------------------------------------------------------
// Fused out-proj + residual(xb bf16) + LayerNorm2 -> yb (bf16 only).
// 32 rows/block (2 row-frags/wave), grid 256.
// ---------------------------------------------------------------------------
__global__ __launch_bounds__(256) void oproj_ln(
    const u16* __restrict__ ctx, const u16* __restrict__ wob,
    const float* __restrict__ ob, const u16* __restrict__ xb,
    const float* __restrict__ g2, const float* __restrict__ be2,
    u16* __restrict__ yb)
{
    __shared__ float s1[4][32], s2[4][32];
    const int tid = threadIdx.x, wv = tid >> 6, l = tid & 63;
    const int g = l >> 4, q = l & 15;
    const int rowbase = blockIdx.x * 32;
    f32x4 acc[2][4] = {};
    const u16* Arow = ctx + (size_t)(rowbase + q) * 256 + g * 8;
    const u16* Brow = wob + (size_t)(wv * 64 + q) * 256 + g * 8;

    #pragma unroll 2
    for (int kk = 0; kk < 256; kk += 32) {
        bf16x8 af[2];
        #pragma unroll
        for (int m = 0; m < 2; ++m)
            af[m] = *(const bf16x8*)(Arow + (size_t)m * 16 * 256 + kk);
        #pragma unroll
        for (int n = 0; n < 4; ++n) {
            const bf16x8 bf = *(const bf16x8*)(Brow + (size_t)n * 16 * 256 + kk);
            #pragma unroll
            for (int m = 0; m < 2; ++m)
                acc[m][n] = __builtin_amdgcn_mfma_f32_16x16x32_bf16(bf, af[m], acc[m][n], 0, 0, 0);
        }
    }

    float sum[2] = {0.f, 0.f};
    #pragma unroll
    for (int m = 0; m < 2; ++m) {
        const int row = rowbase + m * 16 + q;
        #pragma unroll
        for (int n = 0; n < 4; ++n) {
            const int col = wv * 64 + n * 16 + g * 4;
            const float4 bv = *(const float4*)(ob + col);
            const uint2 rp = *(const uint2*)(xb + (size_t)row * 256 + col);
            acc[m][n][0] += bv.x + b2f(rp.x & 0xffffu);
            acc[m][n][1] += bv.y + b2f(rp.x >> 16);
            acc[m][n][2] += bv.z + b2f(rp.y & 0xffffu);
            acc[m][n][3] += bv.w + b2f(rp.y >> 16);
            sum[m] += acc[m][n][0] + acc[m][n][1] + acc[m][n][2] + acc[m][n][3];
        }
        sum[m] += __shfl_xor(sum[m], 16);
        sum[m] += __shfl_xor(sum[m], 32);
    }
    if (l < 16) { s1[wv][q] = sum[0]; s1[wv][16 + q] = sum[1]; }
    __syncthreads();
    float mu[2], rs[2];
    #pragma unroll
    for (int m = 0; m < 2; ++m) {
        const int lr = m * 16 + q;
        mu[m] = (s1[0][lr] + s1[1][lr] + s1[2][lr] + s1[3][lr]) * (1.0f / 256);
    }
    float sq[2] = {0.f, 0.f};
    #pragma unroll
    for (int m = 0; m < 2; ++m) {
        #pragma unroll
        for (int n = 0; n < 4; ++n)
            #pragma unroll
            for (int r = 0; r < 4; ++r) {
                const float d = acc[m][n][r] - mu[m];
                sq[m] += d * d;
            }
        sq[m] += __shfl_xor(sq[m], 16);
        sq[m] += __shfl_xor(sq[m], 32);
    }
    if (l < 16) { s2[wv][q] = sq[0]; s2[wv][16 + q] = sq[1]; }
    __syncthreads();
    #pragma unroll
    for (int m = 0; m < 2; ++m) {
        const int lr = m * 16 + q;
        rs[m] = rsqrtf((s2[0][lr] + s2[1][lr] + s2[2][lr] + s2[3][lr]) * (1.0f / 256) + 1e-5f);
    }

    #pragma unroll
    for (int m = 0; m < 2; ++m) {
        const int row = rowbase + m * 16 + q;
        #pragma unroll
        for (int n = 0; n < 4; ++n) {
            const int col = wv * 64 + n * 16 + g * 4;
            const float4 gv = *(const float4*)(g2 + col);
            const float4 b2 = *(const float4*)(be2 + col);
            const float y0 = (acc[m][n][0] - mu[m]) * rs[m] * gv.x + b2.x;
            const float y1 = (acc[m][n][1] - mu[m]) * rs[m] * gv.y + b2.y;
            const float y2 = (acc[m][n][2] - mu[m]) * rs[m] * gv.z + b2.z;
            const float y3 = (acc[m][n][3] - mu[m]) * rs[m] * gv.w + b2.w;
            uint2 pk;
            pk.x = (unsigned)f2b(y0) | ((unsigned)f2b(y1) << 16);
            pk.y = (unsigned)f2b(y2) | ((unsigned)f2b(y3) << 16);
            *(uint2*)(yb + (size_t)row * 256 + col) = pk;
        }
    }
}

// ---------------------------------------------------------------------------
extern "C" void kernel_launch(void* const* d_in, const int* in_sizes, int n_in,
                              void* d_out, int out_size, void* d_ws, size_t ws_size,
                              hipStream_t stream)
{
    const float* src  = (const float*)d_in[0];
    const float* bias = (const float*)d_in[1];
    const float* ipw  = (const float*)d_in[2];
    const float* ipb  = (const float*)d_in[3];
    const float* outw = (const float*)d_in[4];
    const float* outb = (const float*)d_in[5];
    const float* w1   = (const float*)d_in[6];
    const float* b1   = (const float*)d_in[7];
    const float* w2   = (const float*)d_in[8];
    const float* b2   = (const float*)d_in[9];
    const float* g1   = (const float*)d_in[10];
    const float* be1  = (const float*)d_in[11];
    const float* g2   = (const float*)d_in[12];
    const float* be2  = (const float*)d_in[13];

    char* p = (char*)d_ws;
    auto alloc = [&](size_t bytes) -> void* {
        void* r = (void*)p;
        p += (bytes + 255) & ~(size_t)255;
        return r;
    };
    u16*   xb   = (u16*)  alloc((size_t)NROWS * DMODEL * 2);
    u16*   Qh   = (u16*)  alloc((size_t)64 * S_LEN * HDIM * 2);
    u16*   Kb   = (u16*)  alloc((size_t)64 * S_LEN * HDIM * 2);
    u16*   Vt   = (u16*)  alloc((size_t)64 * S_LEN * HDIM * 2);
    u16*   ctx  = (u16*)  alloc((size_t)NROWS * DMODEL * 2);
    u16*   yb   = (u16*)  alloc((size_t)NROWS * DMODEL * 2);
    u16*   hb   = (u16*)  alloc((size_t)NROWS * DFF * 2);
    u16*   wqkv = (u16*)  alloc((size_t)768 * 256 * 2);
    u16*   wob  = (u16*)  alloc((size_t)256 * 256 * 2);
    u16*   w1b  = (u16*)  alloc((size_t)1024 * 256 * 2);
    u16*   w2b  = (u16*)  alloc((size_t)256 * 1024 * 2);
    float* bq   = (float*)alloc(768 * 4);

    prep_kernel<<<2816, 256, 0, stream>>>(src, g1, be1, xb,
                                          ipw, outw, w1, w2, ipb,
                                          wqkv, wob, w1b, w2b, bq);
    gemm_qkv<<<dim3(64, 6), 256, 0, stream>>>(xb, wqkv, bq, Qh, Kb, Vt);
    attn_kernel<<<dim3(64, 16), 256, 0, stream>>>(Qh, Kb, Vt, bias, ctx);
    oproj_ln<<<256, 256, 0, stream>>>(ctx, wob, outb, xb, g2, be2, yb);
    gemm_ffn1<<<dim3(64, 8), 256, 0, stream>>>(yb, w1b, b1, hb);
    gemm_ffn2<<<dim3(64, 4), 256, 0, stream>>>(hb, w2b, b2, yb, (float*)d_out);
}